// Round 1
// baseline (558.139 us; speedup 1.0000x reference)
//
#include <hip/hip_runtime.h>
#include <math.h>

#define BQ 64
#define TBI 3000
#define DBI 128
#define TSW 375
#define TS1 188
#define DSW 192
#define NF 300
#define DMODEL 512
#define EPSLN 1e-5f

// ---------------- Kernel A: depthwise conv -> LN -> dot -> sigmoid => alpha [B,T]
__global__ __launch_bounds__(256) void k_alpha(
    const float* __restrict__ fs, const float* __restrict__ conv_w,
    const float* __restrict__ ln_g, const float* __restrict__ ln_b,
    const float* __restrict__ wp_w, const float* __restrict__ wp_b,
    float* __restrict__ alpha_out)
{
    int wid = threadIdx.x >> 6;
    int lane = threadIdx.x & 63;
    long g = (long)blockIdx.x * 4 + wid;          // row index in [0, B*T)
    if (g >= (long)BQ * TBI) return;
    const float* row = fs + g * DBI;
    float f0 = row[lane], f1 = row[lane + 64];
    float x0 = f0 * conv_w[lane];
    float x1 = f1 * conv_w[lane + 64];
    float s = x0 + x1;
    for (int m = 32; m >= 1; m >>= 1) s += __shfl_xor(s, m, 64);
    float mu = s * (1.0f / 128.0f);
    float d0 = x0 - mu, d1 = x1 - mu;
    float q = d0 * d0 + d1 * d1;
    for (int m = 32; m >= 1; m >>= 1) q += __shfl_xor(q, m, 64);
    float var = q * (1.0f / 128.0f);
    float rs = rsqrtf(var + EPSLN);
    float xn0 = d0 * rs * ln_g[lane] + ln_b[lane];
    float xn1 = d1 * rs * ln_g[lane + 64] + ln_b[lane + 64];
    float z = xn0 * wp_w[lane] + xn1 * wp_w[lane + 64];
    for (int m = 32; m >= 1; m >>= 1) z += __shfl_xor(z, m, 64);
    z += wp_b[0];
    float a = 4.0f / (1.0f + expf(-z));
    if (lane == 0) alpha_out[g] = a;
}

// ---------------- Kernel B: per-batch sums (f64 deterministic) -> r, thr, qty_b
__global__ __launch_bounds__(1024) void k_batchsum(
    const float* __restrict__ alpha, const int* __restrict__ tlen,
    float2* __restrict__ params, float* __restrict__ qtyb)
{
    __shared__ double red[1024];
    int b = blockIdx.x, tid = threadIdx.x;
    const float* ar = alpha + (long)b * TBI;
    double s = 0.0;
    for (int t = tid; t < TBI; t += 1024) s += (double)ar[t];
    red[tid] = s; __syncthreads();
    for (int d = 512; d >= 1; d >>= 1) { if (tid < d) red[tid] += red[tid + d]; __syncthreads(); }
    double sum_a = red[0];
    __syncthreads();
    double tgt = (double)tlen[b];
    double sa = sum_a < 1e-8 ? 1e-8 : sum_a;
    float r = (float)(tgt / sa);
    double s2 = 0.0;
    for (int t = tid; t < TBI; t += 1024) s2 += (double)(ar[t] * r);   // f32 product, f64 sum
    red[tid] = s2; __syncthreads();
    for (int d = 512; d >= 1; d >>= 1) { if (tid < d) red[tid] += red[tid + d]; __syncthreads(); }
    if (tid == 0) {
        float sum_cif = (float)red[0];          // rounds to exactly tgt (== 300.0f)
        float cs = ceilf(sum_cif); if (cs < 1.0f) cs = 1.0f;
        float thr = sum_cif / cs;
        params[b] = make_float2(r, thr);
        qtyb[b] = (float)fabs(sum_a - tgt);
    }
}

// ---------------- Kernel B2: qty_loss = mean over batches
__global__ void k_qty(const float* __restrict__ qtyb, float* __restrict__ out)
{
    float v = qtyb[threadIdx.x & 63];
    for (int m = 32; m >= 1; m >>= 1) v += __shfl_xor(v, m, 64);
    if (threadIdx.x == 0) out[0] = v * (1.0f / (float)BQ);
}

// ---------------- Kernel C: per-batch cumsum scan (c, cum) + searchsorted fire times
__global__ __launch_bounds__(1024) void k_scan(
    const float* __restrict__ alpha, const float2* __restrict__ params,
    float4* __restrict__ c4, float* __restrict__ tcont)
{
    __shared__ float2 sc[TBI];           // .x = cumsum(alpha_cif/thr) = c ; .y = cumsum(alpha_cif) = cum
    __shared__ float2 part[2][1024];
    int b = blockIdx.x, tid = threadIdx.x;
    float2 pp = params[b];
    float r = pp.x, thr = pp.y;
    const float* ar = alpha + (long)b * TBI;
    int base = tid * 3;
    float2 run = make_float2(0.f, 0.f);
    if (base < TBI) {
        for (int j = 0; j < 3; ++j) {
            int t = base + j;
            float ac = ar[t] * r;        // alpha_cif
            float av = ac / thr;         // a = alpha_cif / thr
            run.x += av; run.y += ac;
            sc[t] = run;
        }
    }
    part[0][tid] = (base < TBI) ? run : make_float2(0.f, 0.f);
    __syncthreads();
    int srcb = 0;
    for (int d = 1; d < 1024; d <<= 1) {
        float2 v = part[srcb][tid];
        if (tid >= d) { float2 u = part[srcb][tid - d]; v.x += u.x; v.y += u.y; }
        part[srcb ^ 1][tid] = v;
        srcb ^= 1;
        __syncthreads();
    }
    if (base < TBI && tid > 0) {
        float2 off = part[srcb][tid - 1];
        for (int j = 0; j < 3; ++j) { sc[base + j].x += off.x; sc[base + j].y += off.y; }
    }
    __syncthreads();
    // persist per-frame record: (c, cum, alpha_cif, a)
    for (int t = tid; t < TBI; t += 1024) {
        float ac = ar[t] * r;
        float2 v = sc[t];
        c4[(long)b * TBI + t] = make_float4(v.x, v.y, ac, ac / thr);
    }
    // searchsorted(cum, (k+1)*thr) -> continuous fire times
    if (tid < NF) {
        float v = (float)(tid + 1) * thr;
        int lo = 0, hi = TBI;
        while (lo < hi) { int mid = (lo + hi) >> 1; if (sc[mid].y < v) lo = mid + 1; else hi = mid; }
        int ff = lo; if (ff > TBI - 1) ff = TBI - 1;
        int tl = ff - 1; if (tl < 0) tl = 0;
        float cum_at = sc[tl].y;
        float a_at = ar[ff] * r;
        if (a_at < 1e-8f) a_at = 1e-8f;
        float tc = (float)tl + (v - cum_at) / a_at;
        tc = fminf(fmaxf(tc, 0.0f), (float)(TBI - 1));
        tcont[b * NF + tid] = tc;
    }
}

// ---------------- Kernel D: CIF scatter-integrate into acoustic_temporal [B,NF,128]
#define FPW 94   // frames per wave, 32 waves per batch (32*94 = 3008 >= 3000)
__global__ __launch_bounds__(256) void k_cif(
    const float* __restrict__ fs, const float4* __restrict__ c4,
    const float2* __restrict__ params, float* __restrict__ at)
{
    int wid = threadIdx.x >> 6, lane = threadIdx.x & 63;
    int wg = blockIdx.x * 4 + wid;          // 0..2047
    int b = wg >> 5, slot = wg & 31;
    int t0 = slot * FPW;
    int t1 = t0 + FPW; if (t1 > TBI) t1 = TBI;
    float thr = params[b].y;
    const float4* cb = c4 + (long)b * TBI;
    const float* fb = fs + (long)b * TBI * DBI;
    float* ab = at + (long)b * NF * DBI;
    int cur = -1;
    float a0 = 0.f, a1 = 0.f;
    for (int t = t0; t < t1; ++t) {
        float4 v = cb[t];
        float c = v.x, ac = v.z, av = v.w;
        float prev = c - av;
        float kp = floorf(prev), kc = floorf(c);
        bool fired = kc > kp;
        float w_lo = fired ? (kp + 1.0f - prev) * thr : ac;
        float w_hi = fired ? (c - kc) * thr : 0.0f;
        int ip = (int)kp; if (ip > NF - 1) ip = NF - 1; if (ip < 0) ip = 0;
        int ic = (int)kc; if (ic > NF - 1) ic = NF - 1; if (ic < 0) ic = 0;
        float h0 = fb[(long)t * DBI + lane], h1 = fb[(long)t * DBI + 64 + lane];
        if (ip != cur) {
            if (cur >= 0) { atomicAdd(&ab[cur * DBI + lane], a0); atomicAdd(&ab[cur * DBI + 64 + lane], a1); }
            cur = ip; a0 = 0.f; a1 = 0.f;
        }
        a0 += w_lo * h0; a1 += w_lo * h1;
        if (fired) {
            if (ic != cur) {
                if (cur >= 0) { atomicAdd(&ab[cur * DBI + lane], a0); atomicAdd(&ab[cur * DBI + 64 + lane], a1); }
                cur = ic; a0 = 0.f; a1 = 0.f;
            }
            a0 += w_hi * h0; a1 += w_hi * h1;
        }
    }
    if (cur >= 0) { atomicAdd(&ab[cur * DBI + lane], a0); atomicAdd(&ab[cur * DBI + 64 + lane], a1); }
}

// ---------------- Kernel E: FiLM + interp + three projections, fused
__global__ __launch_bounds__(256) void k_emb(
    const float* __restrict__ at, const float* __restrict__ tcont,
    const float* __restrict__ src0, const float* __restrict__ src1,
    const float* __restrict__ f0w, const float* __restrict__ f0b,
    const float* __restrict__ f1w, const float* __restrict__ f1b,
    const float* __restrict__ tw, const float* __restrict__ tb,
    const float* __restrict__ aw, const float* __restrict__ apb,
    const float* __restrict__ bw, const float* __restrict__ bpb,
    float* __restrict__ embs)
{
    __shared__ float s[16][DMODEL];   // [at(128) | pitch_mod(192) | beat_mod(192)]
    __shared__ float tl[16];
    __shared__ int rb[16];
    int tid = threadIdx.x;
    long g0 = (long)blockIdx.x * 16;
    for (int idx = tid; idx < 16 * DBI; idx += 256) {
        int r2 = idx >> 7, k = idx & 127;
        s[r2][k] = at[(g0 + r2) * DBI + k];
    }
    if (tid < 16) {
        long g = g0 + tid;
        rb[tid] = (int)(g / NF);
        tl[tid] = tcont[g];
    }
    __syncthreads();
    // Phase A: film0/film1 + interp -> pitch_mod/beat_mod into s[:,128:512]
    for (int iter = 0; iter < 2; ++iter) {
        int c2 = tid + iter * 256;
        if (c2 >= 2 * DSW) break;
        bool sel = c2 >= DSW;
        int j = sel ? c2 - DSW : c2;
        const float* W  = sel ? f1w : f0w;
        const float* Bv = sel ? f1b : f0b;
        const float* S  = sel ? src1 : src0;
        int Ts = sel ? TS1 : TSW;
        float accg[16], accb[16];
        #pragma unroll
        for (int r = 0; r < 16; ++r) { accg[r] = 0.f; accb[r] = 0.f; }
        for (int k4 = 0; k4 < DBI / 4; ++k4) {
            float wg[4], wb[4];
            #pragma unroll
            for (int kk = 0; kk < 4; ++kk) {
                wg[kk] = W[(k4 * 4 + kk) * (2 * DSW) + j];
                wb[kk] = W[(k4 * 4 + kk) * (2 * DSW) + j + DSW];
            }
            #pragma unroll
            for (int r = 0; r < 16; ++r) {
                float4 a4 = *(const float4*)&s[r][k4 * 4];
                accg[r] += a4.x * wg[0] + a4.y * wg[1] + a4.z * wg[2] + a4.w * wg[3];
                accb[r] += a4.x * wb[0] + a4.y * wb[1] + a4.z * wb[2] + a4.w * wb[3];
            }
        }
        float bg = Bv[j], bb2 = Bv[j + DSW];
        float scaleT = (float)Ts;
        #pragma unroll
        for (int r = 0; r < 16; ++r) {
            int bb_ = rb[r];
            float t = tl[r] * scaleT / 3000.0f;
            int lo = (int)t; if (lo > Ts - 2) lo = Ts - 2; if (lo < 0) lo = 0;
            float w = t - (float)lo;
            const float* Sb = S + ((long)bb_ * Ts + lo) * DSW;
            float gl = Sb[j], gh = Sb[DSW + j];
            float pv = (1.0f - w) * gl + w * gh;
            float pm = (accg[r] + bg) * pv + (accb[r] + bb2);
            s[r][DBI + (sel ? DSW : 0) + j] = pm;
        }
    }
    __syncthreads();
    // Phase B: embs = [at|pm|bm] @ [tw;aw;bw] + (tb+apb+bpb)
    int c = tid;
    float acc0[16], acc1[16];
    #pragma unroll
    for (int r = 0; r < 16; ++r) { acc0[r] = 0.f; acc1[r] = 0.f; }
    for (int k4 = 0; k4 < DMODEL / 4; ++k4) {
        int k = k4 * 4;
        const float* Wr;
        if (k < DBI)            Wr = tw + (long)k * DMODEL;
        else if (k < DBI + DSW) Wr = aw + (long)(k - DBI) * DMODEL;
        else                    Wr = bw + (long)(k - DBI - DSW) * DMODEL;
        float w0[4], w1[4];
        #pragma unroll
        for (int kk = 0; kk < 4; ++kk) {
            w0[kk] = Wr[kk * DMODEL + c];
            w1[kk] = Wr[kk * DMODEL + c + 256];
        }
        #pragma unroll
        for (int r = 0; r < 16; ++r) {
            float4 a4 = *(const float4*)&s[r][k];
            acc0[r] += a4.x * w0[0] + a4.y * w0[1] + a4.z * w0[2] + a4.w * w0[3];
            acc1[r] += a4.x * w1[0] + a4.y * w1[1] + a4.z * w1[2] + a4.w * w1[3];
        }
    }
    float bias0 = tb[c] + apb[c] + bpb[c];
    float bias1 = tb[c + 256] + apb[c + 256] + bpb[c + 256];
    #pragma unroll
    for (int r = 0; r < 16; ++r) {
        embs[(g0 + r) * DMODEL + c] = acc0[r] + bias0;
        embs[(g0 + r) * DMODEL + c + 256] = acc1[r] + bias1;
    }
}

extern "C" void kernel_launch(void* const* d_in, const int* in_sizes, int n_in,
                              void* d_out, int out_size, void* d_ws, size_t ws_size,
                              hipStream_t stream)
{
    const float* fs     = (const float*)d_in[0];
    const float* src0   = (const float*)d_in[1];
    const float* src1   = (const float*)d_in[2];
    const int*   tlen   = (const int*)d_in[3];
    const float* conv_w = (const float*)d_in[4];
    const float* ln_g   = (const float*)d_in[5];
    const float* ln_b   = (const float*)d_in[6];
    const float* wp_w   = (const float*)d_in[7];
    const float* wp_b   = (const float*)d_in[8];
    const float* f0w    = (const float*)d_in[9];
    const float* f0b    = (const float*)d_in[10];
    const float* f1w    = (const float*)d_in[11];
    const float* f1b    = (const float*)d_in[12];
    const float* tw     = (const float*)d_in[13];
    const float* tb     = (const float*)d_in[14];
    const float* aw     = (const float*)d_in[15];
    const float* apb    = (const float*)d_in[16];
    const float* bw     = (const float*)d_in[17];
    const float* bpb    = (const float*)d_in[18];

    float* embs  = (float*)d_out;
    float* alpha = embs + (long)BQ * NF * DMODEL;    // offset 9,830,400
    float* qtyo  = alpha + (long)BQ * TBI;           // offset 10,022,400

    char* ws = (char*)d_ws;
    float*  at     = (float*)ws;                                  // 9,830,400 B
    float4* c4     = (float4*)(ws + 9830400);                     // 3,072,000 B
    float*  tcont  = (float*)(ws + 9830400 + 3072000);            //    76,800 B
    float2* params = (float2*)(ws + 9830400 + 3072000 + 76800);   //       512 B
    float*  qtyb   = (float*)(ws + 9830400 + 3072000 + 76800 + 512);

    hipMemsetAsync(at, 0, (size_t)BQ * NF * DBI * sizeof(float), stream);
    k_alpha<<<(BQ * TBI) / 4, 256, 0, stream>>>(fs, conv_w, ln_g, ln_b, wp_w, wp_b, alpha);
    k_batchsum<<<BQ, 1024, 0, stream>>>(alpha, tlen, params, qtyb);
    k_qty<<<1, 64, 0, stream>>>(qtyb, qtyo);
    k_scan<<<BQ, 1024, 0, stream>>>(alpha, params, c4, tcont);
    k_cif<<<512, 256, 0, stream>>>(fs, c4, params, at);
    k_emb<<<(BQ * NF) / 16, 256, 0, stream>>>(at, tcont, src0, src1,
                                              f0w, f0b, f1w, f1b,
                                              tw, tb, aw, apb, bw, bpb, embs);
}

// Round 2
// 324.406 us; speedup vs baseline: 1.7205x; 1.7205x over previous
//
#include <hip/hip_runtime.h>
#include <math.h>

#define BQ 64
#define TBI 3000
#define DBI 128
#define TSW 375
#define TS1 188
#define DSW 192
#define NF 300
#define DMODEL 512
#define EPSLN 1e-5f

typedef __bf16 bf16x8 __attribute__((ext_vector_type(8)));
typedef float f32x4 __attribute__((ext_vector_type(4)));

__device__ __forceinline__ unsigned short f2bf(float f) {
    unsigned u = __float_as_uint(f);
    unsigned r = (u + 0x7FFFu + ((u >> 16) & 1u)) >> 16;
    return (unsigned short)r;
}

// ---------------- Kernel A: depthwise conv -> LN -> dot -> sigmoid => alpha [B,T]
__global__ __launch_bounds__(256) void k_alpha(
    const float* __restrict__ fs, const float* __restrict__ conv_w,
    const float* __restrict__ ln_g, const float* __restrict__ ln_b,
    const float* __restrict__ wp_w, const float* __restrict__ wp_b,
    float* __restrict__ alpha_out)
{
    int wid = threadIdx.x >> 6;
    int lane = threadIdx.x & 63;
    long g = (long)blockIdx.x * 4 + wid;
    if (g >= (long)BQ * TBI) return;
    const float* row = fs + g * DBI;
    float f0 = row[lane], f1 = row[lane + 64];
    float x0 = f0 * conv_w[lane];
    float x1 = f1 * conv_w[lane + 64];
    float s = x0 + x1;
    for (int m = 32; m >= 1; m >>= 1) s += __shfl_xor(s, m, 64);
    float mu = s * (1.0f / 128.0f);
    float d0 = x0 - mu, d1 = x1 - mu;
    float q = d0 * d0 + d1 * d1;
    for (int m = 32; m >= 1; m >>= 1) q += __shfl_xor(q, m, 64);
    float var = q * (1.0f / 128.0f);
    float rs = rsqrtf(var + EPSLN);
    float xn0 = d0 * rs * ln_g[lane] + ln_b[lane];
    float xn1 = d1 * rs * ln_g[lane + 64] + ln_b[lane + 64];
    float z = xn0 * wp_w[lane] + xn1 * wp_w[lane + 64];
    for (int m = 32; m >= 1; m >>= 1) z += __shfl_xor(z, m, 64);
    z += wp_b[0];
    float a = 4.0f / (1.0f + expf(-z));
    if (lane == 0) alpha_out[g] = a;
}

// ---------------- Kernel B: per-batch sums (f64 deterministic) -> r, thr, qty_b
__global__ __launch_bounds__(1024) void k_batchsum(
    const float* __restrict__ alpha, const int* __restrict__ tlen,
    float2* __restrict__ params, float* __restrict__ qtyb)
{
    __shared__ double red[1024];
    int b = blockIdx.x, tid = threadIdx.x;
    const float* ar = alpha + (long)b * TBI;
    double s = 0.0;
    for (int t = tid; t < TBI; t += 1024) s += (double)ar[t];
    red[tid] = s; __syncthreads();
    for (int d = 512; d >= 1; d >>= 1) { if (tid < d) red[tid] += red[tid + d]; __syncthreads(); }
    double sum_a = red[0];
    __syncthreads();
    double tgt = (double)tlen[b];
    double sa = sum_a < 1e-8 ? 1e-8 : sum_a;
    float r = (float)(tgt / sa);
    double s2 = 0.0;
    for (int t = tid; t < TBI; t += 1024) s2 += (double)(ar[t] * r);
    red[tid] = s2; __syncthreads();
    for (int d = 512; d >= 1; d >>= 1) { if (tid < d) red[tid] += red[tid + d]; __syncthreads(); }
    if (tid == 0) {
        float sum_cif = (float)red[0];
        float cs = ceilf(sum_cif); if (cs < 1.0f) cs = 1.0f;
        float thr = sum_cif / cs;
        params[b] = make_float2(r, thr);
        qtyb[b] = (float)fabs(sum_a - tgt);
    }
}

// ---------------- Kernel B2: qty_loss = mean over batches
__global__ void k_qty(const float* __restrict__ qtyb, float* __restrict__ out)
{
    float v = qtyb[threadIdx.x & 63];
    for (int m = 32; m >= 1; m >>= 1) v += __shfl_xor(v, m, 64);
    if (threadIdx.x == 0) out[0] = v * (1.0f / (float)BQ);
}

// ---------------- Kernel C: per-batch cumsum scan + searchsorted fire times
__global__ __launch_bounds__(1024) void k_scan(
    const float* __restrict__ alpha, const float2* __restrict__ params,
    float2* __restrict__ c2, float* __restrict__ tcont)
{
    __shared__ float2 sc[TBI];           // .x = cumsum(alpha_cif/thr) ; .y = cumsum(alpha_cif)
    __shared__ float2 part[2][1024];
    int b = blockIdx.x, tid = threadIdx.x;
    float2 pp = params[b];
    float r = pp.x, thr = pp.y;
    const float* ar = alpha + (long)b * TBI;
    int base = tid * 3;
    float2 run = make_float2(0.f, 0.f);
    if (base < TBI) {
        for (int j = 0; j < 3; ++j) {
            int t = base + j;
            float ac = ar[t] * r;
            float av = ac / thr;
            run.x += av; run.y += ac;
            sc[t] = run;
        }
    }
    part[0][tid] = (base < TBI) ? run : make_float2(0.f, 0.f);
    __syncthreads();
    int srcb = 0;
    for (int d = 1; d < 1024; d <<= 1) {
        float2 v = part[srcb][tid];
        if (tid >= d) { float2 u = part[srcb][tid - d]; v.x += u.x; v.y += u.y; }
        part[srcb ^ 1][tid] = v;
        srcb ^= 1;
        __syncthreads();
    }
    if (base < TBI && tid > 0) {
        float2 off = part[srcb][tid - 1];
        for (int j = 0; j < 3; ++j) { sc[base + j].x += off.x; sc[base + j].y += off.y; }
    }
    __syncthreads();
    // persist per-frame record: (c, alpha_cif)
    for (int t = tid; t < TBI; t += 1024) {
        float ac = ar[t] * r;
        c2[(long)b * TBI + t] = make_float2(sc[t].x, ac);
    }
    // searchsorted(cum, (k+1)*thr) -> continuous fire times
    if (tid < NF) {
        float v = (float)(tid + 1) * thr;
        int lo = 0, hi = TBI;
        while (lo < hi) { int mid = (lo + hi) >> 1; if (sc[mid].y < v) lo = mid + 1; else hi = mid; }
        int ff = lo; if (ff > TBI - 1) ff = TBI - 1;
        int tl = ff - 1; if (tl < 0) tl = 0;
        float cum_at = sc[tl].y;
        float a_at = ar[ff] * r;
        if (a_at < 1e-8f) a_at = 1e-8f;
        float tc = (float)tl + (v - cum_at) / a_at;
        tc = fminf(fmaxf(tc, 0.0f), (float)(TBI - 1));
        tcont[b * NF + tid] = tc;
    }
}

// ---------------- Kernel D: CIF scatter-integrate into acoustic_temporal [B,NF,128]
#define FPW 94
__global__ __launch_bounds__(256) void k_cif(
    const float* __restrict__ fs, const float2* __restrict__ c2,
    const float2* __restrict__ params, float* __restrict__ at)
{
    int wid = threadIdx.x >> 6, lane = threadIdx.x & 63;
    int wg = blockIdx.x * 4 + wid;
    int b = wg >> 5, slot = wg & 31;
    int t0 = slot * FPW;
    int t1 = t0 + FPW; if (t1 > TBI) t1 = TBI;
    float thr = params[b].y;
    const float2* cb = c2 + (long)b * TBI;
    const float* fb = fs + (long)b * TBI * DBI;
    float* ab = at + (long)b * NF * DBI;
    int cur = -1;
    float a0 = 0.f, a1 = 0.f;
    for (int t = t0; t < t1; ++t) {
        float2 v = cb[t];
        float c = v.x, ac = v.y;
        float av = ac / thr;
        float prev = c - av;
        float kp = floorf(prev), kc = floorf(c);
        bool fired = kc > kp;
        float w_lo = fired ? (kp + 1.0f - prev) * thr : ac;
        float w_hi = fired ? (c - kc) * thr : 0.0f;
        int ip = (int)kp; if (ip > NF - 1) ip = NF - 1; if (ip < 0) ip = 0;
        int ic = (int)kc; if (ic > NF - 1) ic = NF - 1; if (ic < 0) ic = 0;
        float h0 = fb[(long)t * DBI + lane], h1 = fb[(long)t * DBI + 64 + lane];
        if (ip != cur) {
            if (cur >= 0) { atomicAdd(&ab[cur * DBI + lane], a0); atomicAdd(&ab[cur * DBI + 64 + lane], a1); }
            cur = ip; a0 = 0.f; a1 = 0.f;
        }
        a0 += w_lo * h0; a1 += w_lo * h1;
        if (fired) {
            if (ic != cur) {
                if (cur >= 0) { atomicAdd(&ab[cur * DBI + lane], a0); atomicAdd(&ab[cur * DBI + 64 + lane], a1); }
                cur = ic; a0 = 0.f; a1 = 0.f;
            }
            a0 += w_hi * h0; a1 += w_hi * h1;
        }
    }
    if (cur >= 0) { atomicAdd(&ab[cur * DBI + lane], a0); atomicAdd(&ab[cur * DBI + 64 + lane], a1); }
}

// ---------------- Prep: swizzle weights into MFMA B-fragment order (bf16)
// frag element (nt,kt,lane,j) at ((nt*KT+kt)*64+lane)*8+j holds W[kt*32+(lane>>4)*8+j][nt*16+(lane&15)]
__global__ __launch_bounds__(256) void k_prep(
    const float* __restrict__ f0w, const float* __restrict__ f1w,
    const float* __restrict__ tw, const float* __restrict__ aw, const float* __restrict__ bw,
    unsigned short* __restrict__ Wg, unsigned short* __restrict__ Wb,
    unsigned short* __restrict__ W2)
{
    int i = blockIdx.x * 256 + threadIdx.x;
    if (i < 49152) {                       // film gamma/beta: K=128 (KT=4), N=384 (NT=24)
        int j = i & 7, lane = (i >> 3) & 63, kt = (i >> 9) & 3, nt = i >> 11;
        int k = kt * 32 + (lane >> 4) * 8 + j;
        int n = nt * 16 + (lane & 15);
        float g, b;
        if (n < 192) { g = f0w[k * 384 + n];         b = f0w[k * 384 + n + 192]; }
        else         { g = f1w[k * 384 + (n - 192)]; b = f1w[k * 384 + (n - 192) + 192]; }
        Wg[i] = f2bf(g); Wb[i] = f2bf(b);
    } else if (i < 49152 + 262144) {       // W2 stacked [tw;aw;bw]: K=512 (KT=16), N=512 (NT=32)
        int ii = i - 49152;
        int j = ii & 7, lane = (ii >> 3) & 63, kt = (ii >> 9) & 15, nt = ii >> 13;
        int k = kt * 32 + (lane >> 4) * 8 + j;
        int n = nt * 16 + (lane & 15);
        float v;
        if (k < 128)      v = tw[k * 512 + n];
        else if (k < 320) v = aw[(k - 128) * 512 + n];
        else              v = bw[(k - 320) * 512 + n];
        W2[ii] = f2bf(v);
    }
}

__global__ void k_prepb(const float* __restrict__ f0b, const float* __restrict__ f1b,
                        const float* __restrict__ tb, const float* __restrict__ apb,
                        const float* __restrict__ bpb,
                        float* __restrict__ gbias, float* __restrict__ bbias,
                        float* __restrict__ bias2)
{
    int c = threadIdx.x;
    if (c < 384) {
        gbias[c] = c < 192 ? f0b[c] : f1b[c - 192];
        bbias[c] = c < 192 ? f0b[c + 192] : f1b[c - 192 + 192];
    }
    bias2[c] = tb[c] + apb[c] + bpb[c];
}

// ---------------- Kernel E (MFMA): FiLM + interp + three projections, fused
#define ROWS 32
__global__ __launch_bounds__(256) void k_emb2(
    const float* __restrict__ at, const float* __restrict__ tcont,
    const float* __restrict__ src0, const float* __restrict__ src1,
    const unsigned short* __restrict__ Wg, const unsigned short* __restrict__ Wb,
    const unsigned short* __restrict__ W2,
    const float* __restrict__ gbias, const float* __restrict__ bbias,
    const float* __restrict__ bias2, float* __restrict__ embs)
{
    __shared__ __align__(16) unsigned short X[ROWS][520];  // [at(128)|pm(192)|bm(192)] bf16, pad 8
    __shared__ float s_w0[ROWS], s_w1[ROWS];
    __shared__ int s_lo0[ROWS], s_lo1[ROWS], s_b[ROWS];
    int tid = threadIdx.x;
    int wave = tid >> 6, lane = tid & 63;
    long r0 = (long)blockIdx.x * ROWS;
    // stage at -> bf16 into X[:,0:128]
    for (int idx = tid; idx < ROWS * 32; idx += 256) {
        int r = idx >> 5, k4 = (idx & 31) * 4;
        float4 v = *(const float4*)&at[(r0 + r) * DBI + k4];
        X[r][k4 + 0] = f2bf(v.x); X[r][k4 + 1] = f2bf(v.y);
        X[r][k4 + 2] = f2bf(v.z); X[r][k4 + 3] = f2bf(v.w);
    }
    if (tid < ROWS) {
        long g = r0 + tid;
        s_b[tid] = (int)(g / NF);
        float tc = tcont[g];
        float t0 = tc * ((float)TSW / 3000.0f);
        int lo0 = (int)t0; if (lo0 > TSW - 2) lo0 = TSW - 2; if (lo0 < 0) lo0 = 0;
        s_lo0[tid] = lo0; s_w0[tid] = t0 - (float)lo0;
        float t1 = tc * ((float)TS1 / 3000.0f);
        int lo1 = (int)t1; if (lo1 > TS1 - 2) lo1 = TS1 - 2; if (lo1 < 0) lo1 = 0;
        s_lo1[tid] = lo1; s_w1[tid] = t1 - (float)lo1;
    }
    __syncthreads();
    int mrow = lane & 15, quad = lane >> 4;
    // ---- Phase 1: film GEMM (gamma+beta) + interp/FiLM epilogue -> X[:,128:512] bf16
    for (int nt = wave; nt < 24; nt += 4) {
        f32x4 ag0 = {0,0,0,0}, ag1 = {0,0,0,0}, ab0 = {0,0,0,0}, ab1 = {0,0,0,0};
        #pragma unroll
        for (int kt = 0; kt < 4; ++kt) {
            bf16x8 a0 = *(const bf16x8*)&X[mrow][kt * 32 + quad * 8];
            bf16x8 a1 = *(const bf16x8*)&X[16 + mrow][kt * 32 + quad * 8];
            bf16x8 bg = *(const bf16x8*)&Wg[(((nt * 4 + kt) * 64) + lane) * 8];
            bf16x8 bb = *(const bf16x8*)&Wb[(((nt * 4 + kt) * 64) + lane) * 8];
            ag0 = __builtin_amdgcn_mfma_f32_16x16x32_bf16(a0, bg, ag0, 0, 0, 0);
            ag1 = __builtin_amdgcn_mfma_f32_16x16x32_bf16(a1, bg, ag1, 0, 0, 0);
            ab0 = __builtin_amdgcn_mfma_f32_16x16x32_bf16(a0, bb, ab0, 0, 0, 0);
            ab1 = __builtin_amdgcn_mfma_f32_16x16x32_bf16(a1, bb, ab1, 0, 0, 0);
        }
        int c = nt * 16 + mrow;            // 0..383
        bool sel = c >= DSW;
        int cc = sel ? c - DSW : c;
        const float* S = sel ? src1 : src0;
        int Ts = sel ? TS1 : TSW;
        float gb = gbias[c], bbv = bbias[c];
        #pragma unroll
        for (int m = 0; m < 2; ++m) {
            #pragma unroll
            for (int q = 0; q < 4; ++q) {
                int r = m * 16 + quad * 4 + q;
                int b = s_b[r];
                int lo = sel ? s_lo1[r] : s_lo0[r];
                float w = sel ? s_w1[r] : s_w0[r];
                const float* Sp = S + ((long)b * Ts + lo) * DSW + cc;
                float pv = (1.0f - w) * Sp[0] + w * Sp[DSW];
                float gv = (m ? ag1[q] : ag0[q]) + gb;
                float bv = (m ? ab1[q] : ab0[q]) + bbv;
                X[r][128 + c] = f2bf(gv * pv + bv);
            }
        }
    }
    __syncthreads();
    // ---- Phase 2: embs[32,512] = X[32,512] @ W2[512,512] + bias2
    #pragma unroll
    for (int chunk = 0; chunk < 2; ++chunk) {
        f32x4 acc[2][4];
        #pragma unroll
        for (int m = 0; m < 2; ++m)
            #pragma unroll
            for (int n = 0; n < 4; ++n) acc[m][n] = (f32x4){0, 0, 0, 0};
        for (int kt = 0; kt < 16; ++kt) {
            bf16x8 a0 = *(const bf16x8*)&X[mrow][kt * 32 + quad * 8];
            bf16x8 a1 = *(const bf16x8*)&X[16 + mrow][kt * 32 + quad * 8];
            #pragma unroll
            for (int n = 0; n < 4; ++n) {
                int nt = wave * 8 + chunk * 4 + n;
                bf16x8 bfv = *(const bf16x8*)&W2[(((nt * 16 + kt) * 64) + lane) * 8];
                acc[0][n] = __builtin_amdgcn_mfma_f32_16x16x32_bf16(a0, bfv, acc[0][n], 0, 0, 0);
                acc[1][n] = __builtin_amdgcn_mfma_f32_16x16x32_bf16(a1, bfv, acc[1][n], 0, 0, 0);
            }
        }
        #pragma unroll
        for (int n = 0; n < 4; ++n) {
            int cbase = (wave * 8 + chunk * 4 + n) * 16 + mrow;
            float bv = bias2[cbase];
            #pragma unroll
            for (int m = 0; m < 2; ++m)
                #pragma unroll
                for (int q = 0; q < 4; ++q) {
                    int r = m * 16 + quad * 4 + q;
                    embs[(r0 + r) * DMODEL + cbase] = acc[m][n][q] + bv;
                }
        }
    }
}

extern "C" void kernel_launch(void* const* d_in, const int* in_sizes, int n_in,
                              void* d_out, int out_size, void* d_ws, size_t ws_size,
                              hipStream_t stream)
{
    const float* fs     = (const float*)d_in[0];
    const float* src0   = (const float*)d_in[1];
    const float* src1   = (const float*)d_in[2];
    const int*   tlen   = (const int*)d_in[3];
    const float* conv_w = (const float*)d_in[4];
    const float* ln_g   = (const float*)d_in[5];
    const float* ln_b   = (const float*)d_in[6];
    const float* wp_w   = (const float*)d_in[7];
    const float* wp_b   = (const float*)d_in[8];
    const float* f0w    = (const float*)d_in[9];
    const float* f0b    = (const float*)d_in[10];
    const float* f1w    = (const float*)d_in[11];
    const float* f1b    = (const float*)d_in[12];
    const float* tw     = (const float*)d_in[13];
    const float* tb     = (const float*)d_in[14];
    const float* aw     = (const float*)d_in[15];
    const float* apb    = (const float*)d_in[16];
    const float* bw     = (const float*)d_in[17];
    const float* bpb    = (const float*)d_in[18];

    float* embs  = (float*)d_out;
    float* alpha = embs + (long)BQ * NF * DMODEL;
    float* qtyo  = alpha + (long)BQ * TBI;

    char* ws = (char*)d_ws;
    size_t off = 0;
    float*  at     = (float*)(ws + off);  off += 9830400;            // [B,NF,128] f32
    float2* c2     = (float2*)(ws + off); off += 1536000;            // [B,T] (c, alpha_cif)
    float*  tcont  = (float*)(ws + off);  off += 76800;
    float2* params = (float2*)(ws + off); off += 512;
    float*  qtyb   = (float*)(ws + off);  off += 256;
    unsigned short* Wg = (unsigned short*)(ws + off); off += 98304;  // 24*4*64*8 bf16
    unsigned short* Wb = (unsigned short*)(ws + off); off += 98304;
    unsigned short* W2 = (unsigned short*)(ws + off); off += 524288; // 32*16*64*8 bf16
    float* gbias = (float*)(ws + off); off += 1536;
    float* bbias = (float*)(ws + off); off += 1536;
    float* bias2 = (float*)(ws + off); off += 2048;

    hipMemsetAsync(at, 0, (size_t)BQ * NF * DBI * sizeof(float), stream);
    k_prep<<<1216, 256, 0, stream>>>(f0w, f1w, tw, aw, bw, Wg, Wb, W2);
    k_prepb<<<1, 512, 0, stream>>>(f0b, f1b, tb, apb, bpb, gbias, bbias, bias2);
    k_alpha<<<(BQ * TBI) / 4, 256, 0, stream>>>(fs, conv_w, ln_g, ln_b, wp_w, wp_b, alpha);
    k_batchsum<<<BQ, 1024, 0, stream>>>(alpha, tlen, params, qtyb);
    k_qty<<<1, 64, 0, stream>>>(qtyb, qtyo);
    k_scan<<<BQ, 1024, 0, stream>>>(alpha, params, c2, tcont);
    k_cif<<<512, 256, 0, stream>>>(fs, c2, params, at);
    k_emb2<<<(BQ * NF) / ROWS, 256, 0, stream>>>(at, tcont, src0, src1,
                                                 Wg, Wb, W2, gbias, bbias, bias2, embs);
}